// Round 21
// baseline (115.074 us; speedup 1.0000x reference)
//
#include <hip/hip_runtime.h>
#include <stdint.h>

// ---------------------------------------------------------------------------
// NeighborSearch: data[n,3], queries[m,3], radius scalar.
// Out layout (int32): [0, m*n)   neighbors_index (compacted front, -1 pad)
//                     [m*n, m*n+m+1) row_splits (exclusive prefix of counts)
//
// Fast path (n==m==8192), 3 nodes:
//   memset: counts = 0.
//   K1 fused_interleave (2048x256): R17's no-ballot count + 31 int4 plain
//     stores over [C0, 64M) interleaved. Masks stored CHUNK-MAJOR
//     (masks2[c*8192+q]) -> 512B contiguous per wave section, full-line
//     writes. (R20 audit: query-major 8B stores at 1KB stride = 64B-line
//     RMW ~ +128MB hidden traffic; K1 was HBM-bound on THAT, not on sched.
//     NT stores also falsified: 1.7 TB/s.)
//   K3 scanemit_fill_tail (2048x256): full scan -> rs (verbatim R17);
//     emit reoriented THREAD-PER-QUERY on blocks 0..31 (thread t emits query
//     b*256+t; mask reads masks2[c*8192+q] = 2KB contiguous per block per c);
//     tail fill [L, C0) plain stores.
//   Coverage: emit [0,L) | patch [L,Lr) | K3 [Lr/4, C04) | K1 31 slabs
//     [C04, N4TOT). Max K1 index = C04 + 524287 + 30*SLAB = N4TOT-1. Exact.
// ---------------------------------------------------------------------------

#define N8 8192
#define C0 2097152                    // fill boundary (ints) = 8 MB
#define C04 (C0 / 4)                  // 524288 int4
#define SLAB 524288                   // int4 per slab = 2048 blk x 256 thr
#define N4TOT ((size_t)N8 * N8 / 4)   // 16777216 int4

__device__ __forceinline__ float next_up(float x) {
    return __uint_as_float(__float_as_uint(x) + 1u);
}
__device__ __forceinline__ float next_down(float x) {
    return __uint_as_float(__float_as_uint(x) - 1u);
}

// Largest float T such that correctly-rounded sqrt(T) <= r (r > 0).
// (u <= T) <=> (sqrt_rn(max(u,0)) <= r), since sqrt_rn is monotone.
__device__ __forceinline__ float sq_threshold(float r) {
    float T = __fmul_rn(r, r);
    while (__fsqrt_rn(T) > r) T = next_down(T);
    while (__fsqrt_rn(next_up(T)) <= r) T = next_up(T);
    return T;
}

// Reference arithmetic, exactly (no contraction).
__device__ __forceinline__ float pair_metric(float qx, float qy, float qz, float q2,
                                             float dx, float dy, float dz) {
    float d2 = __fadd_rn(__fadd_rn(__fmul_rn(dx, dx), __fmul_rn(dy, dy)),
                         __fmul_rn(dz, dz));
    float dot = __builtin_fmaf(qz, dz, __builtin_fmaf(qy, dy, __fmul_rn(qx, dx)));
    return __fsub_rn(__fadd_rn(q2, d2), __fmul_rn(2.0f, dot));
}

__device__ __forceinline__ float bc_lane(float x, int j) {
    return __int_as_float(__builtin_amdgcn_readlane(__float_as_int(x), j));
}

// ========================= fast path (8192 x 8192) =========================

// Grid: 2048 x 256. Wave unit u = bid*4+wv: chunk c=u>>6, group g=u&63.
// Lane owns point c*64+lane AND queries g*128+lane / g*128+64+lane.
__global__ __launch_bounds__(256) void fused_interleave(
    const float* __restrict__ data, const float* __restrict__ queries,
    const float* __restrict__ radius_p, int* __restrict__ out_idx,
    unsigned long long* __restrict__ masks2, int* __restrict__ counts) {
    int bid = blockIdx.x;
    int tid = threadIdx.x;
    int lane = tid & 63;
    int wv = tid >> 6;
    int u = bid * 4 + wv;
    int c = u >> 6;
    int g = u & 63;

    float T = sq_threshold(radius_p[0]);

    // lane's point (broadcast source for all lanes)
    int p = c * 64 + lane;
    float dx = data[3 * p + 0], dy = data[3 * p + 1], dz = data[3 * p + 2];
    float d2 = __fadd_rn(__fadd_rn(__fmul_rn(dx, dx), __fmul_rn(dy, dy)),
                         __fmul_rn(dz, dz));

    // lane's two queries (one per section)
    int q0 = g * 128 + lane, q1 = g * 128 + 64 + lane;
    float qx0 = queries[3 * q0 + 0], qy0 = queries[3 * q0 + 1],
          qz0 = queries[3 * q0 + 2];
    float q20 = __fadd_rn(__fadd_rn(__fmul_rn(qx0, qx0), __fmul_rn(qy0, qy0)),
                          __fmul_rn(qz0, qz0));
    float qx1 = queries[3 * q1 + 0], qy1 = queries[3 * q1 + 1],
          qz1 = queries[3 * q1 + 2];
    float q21 = __fadd_rn(__fadd_rn(__fmul_rn(qx1, qx1), __fmul_rn(qy1, qy1)),
                          __fmul_rn(qz1, qz1));

    unsigned long long mask0 = 0, mask1 = 0;

    int4* out4 = (int4*)out_idx;
    const int4 vm1 = make_int4(-1, -1, -1, -1);
    size_t fb = (size_t)C04 + (size_t)bid * 256 + tid;   // fill base

    // Fill region [C04, N4TOT) = exactly 31 slabs; stores k = 0..30 only.
    // ---- section 0: point j vs lane's query q0; store k=j/4 at j%4==0 ----
#pragma unroll
    for (int j = 0; j < 64; ++j) {
        if ((j & 3) == 0)
            out4[fb + (size_t)(j >> 2) * SLAB] = vm1;          // k = 0..15
        float Px = bc_lane(dx, j), Py = bc_lane(dy, j);
        float Pz = bc_lane(dz, j), Pd2 = bc_lane(d2, j);
        float dot = __builtin_fmaf(qz0, Pz,
                      __builtin_fmaf(qy0, Py, __fmul_rn(qx0, Px)));
        float uu = __fsub_rn(__fadd_rn(q20, Pd2), __fmul_rn(2.0f, dot));
        if (uu <= T) mask0 |= (1ull << j);
    }
    // ---- section 1: store k=16+j/4 at j%4==0, j<60 (k = 16..30) ----
#pragma unroll
    for (int j = 0; j < 64; ++j) {
        if ((j & 3) == 0 && j < 60)
            out4[fb + (size_t)(16 + (j >> 2)) * SLAB] = vm1;   // k = 16..30
        float Px = bc_lane(dx, j), Py = bc_lane(dy, j);
        float Pz = bc_lane(dz, j), Pd2 = bc_lane(d2, j);
        float dot = __builtin_fmaf(qz1, Pz,
                      __builtin_fmaf(qy1, Py, __fmul_rn(qx1, Px)));
        float uu = __fsub_rn(__fadd_rn(q21, Pd2), __fmul_rn(2.0f, dot));
        if (uu <= T) mask1 |= (1ull << j);
    }

    // CHUNK-MAJOR mask stores: lanes write 512B contiguous per section.
    masks2[(size_t)c * N8 + q0] = mask0;
    masks2[(size_t)c * N8 + q1] = mask1;
    atomicAdd(&counts[q0], __popcll(mask0));
    atomicAdd(&counts[q1], __popcll(mask1));
}

// Grid: 2048 x 256. Full scan -> rs (verbatim R17); thread-per-query emit on
// blocks 0..31 (coalesced chunk-major mask reads); tail fill [L, C0).
__global__ __launch_bounds__(256) void scanemit_fill_tail(
    const unsigned long long* __restrict__ masks2, const int* __restrict__ counts,
    int* __restrict__ out_idx, int* __restrict__ rs) {
    __shared__ int part[256];
    __shared__ int s_cnt[32];
    __shared__ int cnt256[256];
    int b = blockIdx.x;
    int t = threadIdx.x;

    // ---- full scan of counts over 32-query chunks ----
    int s = 0;
#pragma unroll 8
    for (int k = 0; k < 32; ++k) s += counts[t * 32 + k];
    part[t] = s;
    __syncthreads();
    for (int off = 1; off < 256; off <<= 1) {
        int v = 0;
        if (t >= off) v = part[t - off];
        __syncthreads();
        if (t >= off) part[t] += v;
        __syncthreads();
    }

    // ---- rs writes: block b owns queries b*4..b*4+3 (verbatim R17) ----
    int c32 = b >> 3;
    if (t < 32) s_cnt[t] = counts[c32 * 32 + t];
    __syncthreads();
    if (t < 4) {
        int q = b * 4 + t;
        int excl = (c32 == 0) ? 0 : part[c32 - 1];
        int o = q & 31;
        int sum = 0;
        for (int k = 0; k < o; ++k) sum += s_cnt[k];
        rs[q] = excl + sum;
    }
    if (b == 2047 && t == 0) rs[N8] = part[255];
    int L = part[255];

    // ---- emit: blocks 0..31, thread t emits query q = b*256+t ----
    if (b < 32) {
        cnt256[t] = counts[b * 256 + t];
        __syncthreads();
        int q = b * 256 + t;
        int cq = q >> 5;                      // global 32-query chunk
        int base = (cq == 0) ? 0 : part[cq - 1];
        int lo = t & ~31;
        for (int k = lo; k < t; ++k) base += cnt256[k];
        int pos = base;
        for (int c = 0; c < 128; ++c) {
            unsigned long long mk = masks2[(size_t)c * N8 + q];  // coalesced
            int jb = c * 64;
            while (mk) {
                int bt = __builtin_ctzll(mk);
                out_idx[pos++] = jb + bt;
                mk &= mk - 1;
            }
        }
    }

    // ---- tail fill [L, C0) (K1 fills [C0, 64M)) ----
    int Lr = (L + 3) & ~3;
    if (b == 0 && t < (Lr - L)) out_idx[L + t] = -1;
    int4* out4 = (int4*)out_idx;
    const int4 v = make_int4(-1, -1, -1, -1);
    int i = (Lr >> 2) + b * 256 + t;
    const int stride = 2048 * 256;
    for (; i < C04; i += stride) out4[i] = v;
}

// ====================== generic fallback (round-1 path) ======================

__global__ __launch_bounds__(256) void fill_kernel(int* __restrict__ out, size_t total) {
    size_t n4 = total >> 2;
    int4* out4 = (int4*)out;
    size_t i = (size_t)blockIdx.x * blockDim.x + threadIdx.x;
    size_t stride = (size_t)gridDim.x * blockDim.x;
    const int4 v = make_int4(-1, -1, -1, -1);
    for (; i < n4; i += stride) out4[i] = v;
    if (blockIdx.x == 0 && threadIdx.x == 0) {
        for (size_t k = n4 << 2; k < total; ++k) out[k] = -1;
    }
}

__global__ __launch_bounds__(256) void count_kernel(
    const float* __restrict__ data, const float* __restrict__ queries,
    const float* __restrict__ radius_p, int n, int m, int* __restrict__ counts) {
    int q = (blockIdx.x * blockDim.x + threadIdx.x) >> 6;
    int lane = threadIdx.x & 63;
    if (q >= m) return;
    float r = radius_p[0];
    float T = sq_threshold(r);
    float qx = queries[3 * q + 0], qy = queries[3 * q + 1], qz = queries[3 * q + 2];
    float q2 = __fadd_rn(__fadd_rn(__fmul_rn(qx, qx), __fmul_rn(qy, qy)),
                         __fmul_rn(qz, qz));
    int cnt = 0;
    for (int j = lane; j < n; j += 64) {
        float u = pair_metric(qx, qy, qz, q2, data[3 * j], data[3 * j + 1], data[3 * j + 2]);
        if (u <= T) cnt++;
    }
    for (int off = 32; off > 0; off >>= 1) cnt += __shfl_down(cnt, off, 64);
    if (lane == 0) counts[q] = cnt;
}

__global__ __launch_bounds__(1024) void scan_kernel2(const int* __restrict__ counts,
                                                     int* __restrict__ rs, int m) {
    __shared__ int part[1024];
    int t = threadIdx.x;
    int base = t * 8;
    int c[8];
    int s = 0;
    for (int k = 0; k < 8; ++k) {
        int p = base + k;
        c[k] = (p < m) ? counts[p] : 0;
        s += c[k];
    }
    part[t] = s;
    __syncthreads();
    for (int off = 1; off < 1024; off <<= 1) {
        int v = 0;
        if (t >= off) v = part[t - off];
        __syncthreads();
        if (t >= off) part[t] += v;
        __syncthreads();
    }
    int run = (t == 0) ? 0 : part[t - 1];
    for (int k = 0; k < 8; ++k) {
        int p = base + k;
        if (p < m) rs[p] = run;
        run += c[k];
    }
    if (t == 1023) rs[m] = part[1023];
}

__global__ __launch_bounds__(256) void emit_kernel(
    const float* __restrict__ data, const float* __restrict__ queries,
    const float* __restrict__ radius_p, int n, int m,
    const int* __restrict__ row_splits, int* __restrict__ out_idx) {
    int q = (blockIdx.x * blockDim.x + threadIdx.x) >> 6;
    int lane = threadIdx.x & 63;
    if (q >= m) return;
    float r = radius_p[0];
    float T = sq_threshold(r);
    float qx = queries[3 * q + 0], qy = queries[3 * q + 1], qz = queries[3 * q + 2];
    float q2 = __fadd_rn(__fadd_rn(__fmul_rn(qx, qx), __fmul_rn(qy, qy)),
                         __fmul_rn(qz, qz));
    int base = row_splits[q];
    unsigned long long lane_mask_lt = (lane == 0) ? 0ULL : (~0ULL >> (64 - lane));
    for (int j0 = 0; j0 < n; j0 += 64) {
        int j = j0 + lane;
        bool pred = false;
        if (j < n) {
            float u = pair_metric(qx, qy, qz, q2, data[3 * j], data[3 * j + 1], data[3 * j + 2]);
            pred = (u <= T);
        }
        unsigned long long mask = __ballot(pred);
        if (pred) {
            int pos = base + __popcll(mask & lane_mask_lt);
            out_idx[pos] = j;
        }
        base += __popcll(mask);
    }
}

// ===========================================================================

extern "C" void kernel_launch(void* const* d_in, const int* in_sizes, int n_in,
                              void* d_out, int out_size, void* d_ws, size_t ws_size,
                              hipStream_t stream) {
    const float* data = (const float*)d_in[0];
    const float* queries = (const float*)d_in[1];
    const float* radius = (const float*)d_in[2];
    int n = in_sizes[0] / 3;
    int m = in_sizes[1] / 3;
    int* out = (int*)d_out;
    size_t idx_count = (size_t)m * (size_t)n;
    int* row = out + idx_count;  // m+1 ints

    // ws layout: masks2 (8MB, chunk-major) | counts (32KB)
    size_t mask_bytes = (size_t)N8 * 128 * 8;
    size_t need = mask_bytes + N8 * 4;
    bool fast = (n == N8) && (m == N8) && (ws_size >= need);

    if (fast) {
        unsigned long long* masks2 = (unsigned long long*)d_ws;
        int* counts = (int*)((char*)d_ws + mask_bytes);
        (void)hipMemsetAsync(counts, 0, N8 * sizeof(int), stream);
        fused_interleave<<<2048, 256, 0, stream>>>(data, queries, radius, out,
                                                   masks2, counts);
        scanemit_fill_tail<<<2048, 256, 0, stream>>>(masks2, counts, out, row);
    } else {
        fill_kernel<<<2048, 256, 0, stream>>>(out, idx_count);
        int blocks = (m * 64 + 255) / 256;
        count_kernel<<<blocks, 256, 0, stream>>>(data, queries, radius, n, m, row);
        scan_kernel2<<<1, 1024, 0, stream>>>(row, row, m);
        emit_kernel<<<blocks, 256, 0, stream>>>(data, queries, radius, n, m, row, out);
    }
}

// Round 22
// 67.355 us; speedup vs baseline: 1.7085x; 1.7085x over previous
//
#include <hip/hip_runtime.h>
#include <stdint.h>

// ---------------------------------------------------------------------------
// NeighborSearch: data[n,3], queries[m,3], radius scalar.
// Out layout (int32): [0, m*n)   neighbors_index (compacted front, -1 pad)
//                     [m*n, m*n+m+1) row_splits (exclusive prefix of counts)
//
// Fast path (n==m==8192), 3 nodes:
//   memset: counts = 0.
//   K1 fused_interleave (1024x512, 8 waves): block owns query group g=bid&63
//     and 8 consecutive chunks c=(bid>>6)*8+wv. Per wave: R17's no-ballot
//     count (lane owns query; point broadcast via readlane) + 31 int4 fill
//     stores interleaved. Masks parked in LDS [128][8], then written
//     QUERY-MAJOR as FULL 64B LINES (4 thr x 16B per query row) -> no
//     write-allocate RMW (R20 audit: 8B-per-line scatter cost ~+120MB hidden
//     traffic). Counts: 1 atomicAdd per query per block (8 chunks summed).
//   K3 scanemit_fill_tail (2048x256, VERBATIM R17): scan -> rs, wave-per-
//     query emit from query-major masks, tail fill [L, C0).
//     (R21 lesson: emit must stay spread across all blocks; 32-block emit
//      serialized at ~1 block/CU and cost +43us.)
//   Coverage: emit [0,L) | patch [L,Lr) | K3 [Lr/4, C04) | K1 31 slabs
//     [C04, N4TOT). SLAB = 1024*512 = 524288. Max K1 index = N4TOT-1. Exact.
// ---------------------------------------------------------------------------

#define N8 8192
#define C0 2097152                    // fill boundary (ints) = 8 MB
#define C04 (C0 / 4)                  // 524288 int4
#define SLAB 524288                   // int4 per slab = 1024 blk x 512 thr
#define N4TOT ((size_t)N8 * N8 / 4)   // 16777216 int4

__device__ __forceinline__ float next_up(float x) {
    return __uint_as_float(__float_as_uint(x) + 1u);
}
__device__ __forceinline__ float next_down(float x) {
    return __uint_as_float(__float_as_uint(x) - 1u);
}

// Largest float T such that correctly-rounded sqrt(T) <= r (r > 0).
// (u <= T) <=> (sqrt_rn(max(u,0)) <= r), since sqrt_rn is monotone.
__device__ __forceinline__ float sq_threshold(float r) {
    float T = __fmul_rn(r, r);
    while (__fsqrt_rn(T) > r) T = next_down(T);
    while (__fsqrt_rn(next_up(T)) <= r) T = next_up(T);
    return T;
}

// Reference arithmetic, exactly (no contraction).
__device__ __forceinline__ float pair_metric(float qx, float qy, float qz, float q2,
                                             float dx, float dy, float dz) {
    float d2 = __fadd_rn(__fadd_rn(__fmul_rn(dx, dx), __fmul_rn(dy, dy)),
                         __fmul_rn(dz, dz));
    float dot = __builtin_fmaf(qz, dz, __builtin_fmaf(qy, dy, __fmul_rn(qx, dx)));
    return __fsub_rn(__fadd_rn(q2, d2), __fmul_rn(2.0f, dot));
}

__device__ __forceinline__ float bc_lane(float x, int j) {
    return __int_as_float(__builtin_amdgcn_readlane(__float_as_int(x), j));
}

// ========================= fast path (8192 x 8192) =========================

// Grid: 1024 x 512. Block: g = bid&63, chunks c = (bid>>6)*8 + wv (wv=0..7).
// Lane owns point c*64+lane AND queries g*128+lane / g*128+64+lane.
__global__ __launch_bounds__(512) void fused_interleave(
    const float* __restrict__ data, const float* __restrict__ queries,
    const float* __restrict__ radius_p, int* __restrict__ out_idx,
    unsigned long long* __restrict__ masks, int* __restrict__ counts) {
    __shared__ unsigned long long mask_lds[128][8];   // [q_local][c_local]
    int bid = blockIdx.x;
    int tid = threadIdx.x;
    int lane = tid & 63;
    int wv = tid >> 6;                 // 0..7
    int cb = bid >> 6;                 // 0..15
    int g = bid & 63;                  // query group
    int c = cb * 8 + wv;               // chunk 0..127

    float T = sq_threshold(radius_p[0]);

    // lane's point (broadcast source for all lanes)
    int p = c * 64 + lane;
    float dx = data[3 * p + 0], dy = data[3 * p + 1], dz = data[3 * p + 2];
    float d2 = __fadd_rn(__fadd_rn(__fmul_rn(dx, dx), __fmul_rn(dy, dy)),
                         __fmul_rn(dz, dz));

    // lane's two queries (one per section)
    int q0 = g * 128 + lane, q1 = g * 128 + 64 + lane;
    float qx0 = queries[3 * q0 + 0], qy0 = queries[3 * q0 + 1],
          qz0 = queries[3 * q0 + 2];
    float q20 = __fadd_rn(__fadd_rn(__fmul_rn(qx0, qx0), __fmul_rn(qy0, qy0)),
                          __fmul_rn(qz0, qz0));
    float qx1 = queries[3 * q1 + 0], qy1 = queries[3 * q1 + 1],
          qz1 = queries[3 * q1 + 2];
    float q21 = __fadd_rn(__fadd_rn(__fmul_rn(qx1, qx1), __fmul_rn(qy1, qy1)),
                          __fmul_rn(qz1, qz1));

    unsigned long long mask0 = 0, mask1 = 0;

    int4* out4 = (int4*)out_idx;
    const int4 vm1 = make_int4(-1, -1, -1, -1);
    size_t fb = (size_t)C04 + (size_t)bid * 512 + tid;   // fill base

    // Fill region [C04, N4TOT) = exactly 31 slabs; stores k = 0..30 only.
    // ---- section 0: point j vs lane's query q0; store k=j/4 at j%4==0 ----
#pragma unroll
    for (int j = 0; j < 64; ++j) {
        if ((j & 3) == 0)
            out4[fb + (size_t)(j >> 2) * SLAB] = vm1;          // k = 0..15
        float Px = bc_lane(dx, j), Py = bc_lane(dy, j);
        float Pz = bc_lane(dz, j), Pd2 = bc_lane(d2, j);
        float dot = __builtin_fmaf(qz0, Pz,
                      __builtin_fmaf(qy0, Py, __fmul_rn(qx0, Px)));
        float uu = __fsub_rn(__fadd_rn(q20, Pd2), __fmul_rn(2.0f, dot));
        if (uu <= T) mask0 |= (1ull << j);
    }
    // ---- section 1: store k=16+j/4 at j%4==0, j<60 (k = 16..30) ----
#pragma unroll
    for (int j = 0; j < 64; ++j) {
        if ((j & 3) == 0 && j < 60)
            out4[fb + (size_t)(16 + (j >> 2)) * SLAB] = vm1;   // k = 16..30
        float Px = bc_lane(dx, j), Py = bc_lane(dy, j);
        float Pz = bc_lane(dz, j), Pd2 = bc_lane(d2, j);
        float dot = __builtin_fmaf(qz1, Pz,
                      __builtin_fmaf(qy1, Py, __fmul_rn(qx1, Px)));
        float uu = __fsub_rn(__fadd_rn(q21, Pd2), __fmul_rn(2.0f, dot));
        if (uu <= T) mask1 |= (1ull << j);
    }

    // ---- LDS transpose staging ----
    mask_lds[lane][wv] = mask0;
    mask_lds[64 + lane][wv] = mask1;
    __syncthreads();

    // ---- query-major mask writeout: full 64B lines, no RMW ----
    // thread t: q_local = t>>2, quarter = t&3 -> 16B at q*1KB + cb*64 + q*16
    {
        int q_local = tid >> 2;
        int quarter = tid & 3;
        unsigned long long m0 = mask_lds[q_local][quarter * 2];
        unsigned long long m1 = mask_lds[q_local][quarter * 2 + 1];
        size_t base = (size_t)(g * 128 + q_local) * 128 + cb * 8 + quarter * 2;
        ulonglong2 vv;
        vv.x = m0;
        vv.y = m1;
        *(ulonglong2*)&masks[base] = vv;
    }
    // ---- counts: one atomic per query per block (sum of 8 chunks) ----
    if (tid < 128) {
        int cnt = 0;
#pragma unroll
        for (int k = 0; k < 8; ++k) cnt += __popcll(mask_lds[tid][k]);
        atomicAdd(&counts[g * 128 + tid], cnt);
    }
}

// Grid: 2048 x 256. VERBATIM R17: per-block scan + rs + emit + tail fill.
__global__ __launch_bounds__(256) void scanemit_fill_tail(
    const unsigned long long* __restrict__ masks, const int* __restrict__ counts,
    int* __restrict__ out_idx, int* __restrict__ rs) {
    __shared__ int part[256];
    __shared__ int s_cnt[32];
    __shared__ int s_base[4];
    int b = blockIdx.x;
    int t = threadIdx.x;
    int wave = t >> 6;
    int lane = t & 63;

    int s = 0;
#pragma unroll 8
    for (int k = 0; k < 32; ++k) s += counts[t * 32 + k];
    part[t] = s;
    __syncthreads();
    for (int off = 1; off < 256; off <<= 1) {
        int v = 0;
        if (t >= off) v = part[t - off];
        __syncthreads();
        if (t >= off) part[t] += v;
        __syncthreads();
    }
    int c32 = b >> 3;
    if (t < 32) s_cnt[t] = counts[c32 * 32 + t];
    __syncthreads();
    if (t < 4) {
        int q = b * 4 + t;
        int excl = (c32 == 0) ? 0 : part[c32 - 1];
        int o = q & 31;
        int sum = 0;
        for (int k = 0; k < o; ++k) sum += s_cnt[k];
        int v = excl + sum;
        s_base[t] = v;
        rs[q] = v;
    }
    if (b == 2047 && t == 0) rs[N8] = part[255];
    __syncthreads();
    int L = part[255];

    {
        int q = b * 4 + wave;
        unsigned long long lo = masks[(size_t)q * 128 + lane];
        unsigned long long hi = masks[(size_t)q * 128 + 64 + lane];
        int plo = __popcll(lo), phi = __popcll(hi);
        int ilo = plo, ihi = phi;
        for (int off = 1; off < 64; off <<= 1) {
            int a = __shfl_up(ilo, off, 64);
            int bsh = __shfl_up(ihi, off, 64);
            if (lane >= off) { ilo += a; ihi += bsh; }
        }
        int total_lo = __shfl(ilo, 63, 64);
        int base = s_base[wave];
        int pos_lo = base + ilo - plo;
        int pos_hi = base + total_lo + ihi - phi;
        int jb_lo = lane * 64, jb_hi = (64 + lane) * 64;
        while (lo) {
            int bt = __builtin_ctzll(lo);
            out_idx[pos_lo++] = jb_lo + bt;
            lo &= lo - 1;
        }
        while (hi) {
            int bt = __builtin_ctzll(hi);
            out_idx[pos_hi++] = jb_hi + bt;
            hi &= hi - 1;
        }
    }

    // ---- tail fill [L, C0) (K1 fills [C0, 64M)) ----
    int Lr = (L + 3) & ~3;
    if (b == 0 && t < (Lr - L)) out_idx[L + t] = -1;
    int4* out4 = (int4*)out_idx;
    const int4 v = make_int4(-1, -1, -1, -1);
    int i = (Lr >> 2) + b * 256 + t;
    const int stride = 2048 * 256;
    for (; i < C04; i += stride) out4[i] = v;
}

// ====================== generic fallback (round-1 path) ======================

__global__ __launch_bounds__(256) void fill_kernel(int* __restrict__ out, size_t total) {
    size_t n4 = total >> 2;
    int4* out4 = (int4*)out;
    size_t i = (size_t)blockIdx.x * blockDim.x + threadIdx.x;
    size_t stride = (size_t)gridDim.x * blockDim.x;
    const int4 v = make_int4(-1, -1, -1, -1);
    for (; i < n4; i += stride) out4[i] = v;
    if (blockIdx.x == 0 && threadIdx.x == 0) {
        for (size_t k = n4 << 2; k < total; ++k) out[k] = -1;
    }
}

__global__ __launch_bounds__(256) void count_kernel(
    const float* __restrict__ data, const float* __restrict__ queries,
    const float* __restrict__ radius_p, int n, int m, int* __restrict__ counts) {
    int q = (blockIdx.x * blockDim.x + threadIdx.x) >> 6;
    int lane = threadIdx.x & 63;
    if (q >= m) return;
    float r = radius_p[0];
    float T = sq_threshold(r);
    float qx = queries[3 * q + 0], qy = queries[3 * q + 1], qz = queries[3 * q + 2];
    float q2 = __fadd_rn(__fadd_rn(__fmul_rn(qx, qx), __fmul_rn(qy, qy)),
                         __fmul_rn(qz, qz));
    int cnt = 0;
    for (int j = lane; j < n; j += 64) {
        float u = pair_metric(qx, qy, qz, q2, data[3 * j], data[3 * j + 1], data[3 * j + 2]);
        if (u <= T) cnt++;
    }
    for (int off = 32; off > 0; off >>= 1) cnt += __shfl_down(cnt, off, 64);
    if (lane == 0) counts[q] = cnt;
}

__global__ __launch_bounds__(1024) void scan_kernel2(const int* __restrict__ counts,
                                                     int* __restrict__ rs, int m) {
    __shared__ int part[1024];
    int t = threadIdx.x;
    int base = t * 8;
    int c[8];
    int s = 0;
    for (int k = 0; k < 8; ++k) {
        int p = base + k;
        c[k] = (p < m) ? counts[p] : 0;
        s += c[k];
    }
    part[t] = s;
    __syncthreads();
    for (int off = 1; off < 1024; off <<= 1) {
        int v = 0;
        if (t >= off) v = part[t - off];
        __syncthreads();
        if (t >= off) part[t] += v;
        __syncthreads();
    }
    int run = (t == 0) ? 0 : part[t - 1];
    for (int k = 0; k < 8; ++k) {
        int p = base + k;
        if (p < m) rs[p] = run;
        run += c[k];
    }
    if (t == 1023) rs[m] = part[1023];
}

__global__ __launch_bounds__(256) void emit_kernel(
    const float* __restrict__ data, const float* __restrict__ queries,
    const float* __restrict__ radius_p, int n, int m,
    const int* __restrict__ row_splits, int* __restrict__ out_idx) {
    int q = (blockIdx.x * blockDim.x + threadIdx.x) >> 6;
    int lane = threadIdx.x & 63;
    if (q >= m) return;
    float r = radius_p[0];
    float T = sq_threshold(r);
    float qx = queries[3 * q + 0], qy = queries[3 * q + 1], qz = queries[3 * q + 2];
    float q2 = __fadd_rn(__fadd_rn(__fmul_rn(qx, qx), __fmul_rn(qy, qy)),
                         __fmul_rn(qz, qz));
    int base = row_splits[q];
    unsigned long long lane_mask_lt = (lane == 0) ? 0ULL : (~0ULL >> (64 - lane));
    for (int j0 = 0; j0 < n; j0 += 64) {
        int j = j0 + lane;
        bool pred = false;
        if (j < n) {
            float u = pair_metric(qx, qy, qz, q2, data[3 * j], data[3 * j + 1], data[3 * j + 2]);
            pred = (u <= T);
        }
        unsigned long long mask = __ballot(pred);
        if (pred) {
            int pos = base + __popcll(mask & lane_mask_lt);
            out_idx[pos] = j;
        }
        base += __popcll(mask);
    }
}

// ===========================================================================

extern "C" void kernel_launch(void* const* d_in, const int* in_sizes, int n_in,
                              void* d_out, int out_size, void* d_ws, size_t ws_size,
                              hipStream_t stream) {
    const float* data = (const float*)d_in[0];
    const float* queries = (const float*)d_in[1];
    const float* radius = (const float*)d_in[2];
    int n = in_sizes[0] / 3;
    int m = in_sizes[1] / 3;
    int* out = (int*)d_out;
    size_t idx_count = (size_t)m * (size_t)n;
    int* row = out + idx_count;  // m+1 ints

    // ws layout: masks (8MB, query-major) | counts (32KB)
    size_t mask_bytes = (size_t)N8 * 128 * 8;
    size_t need = mask_bytes + N8 * 4;
    bool fast = (n == N8) && (m == N8) && (ws_size >= need);

    if (fast) {
        unsigned long long* masks = (unsigned long long*)d_ws;
        int* counts = (int*)((char*)d_ws + mask_bytes);
        (void)hipMemsetAsync(counts, 0, N8 * sizeof(int), stream);
        fused_interleave<<<1024, 512, 0, stream>>>(data, queries, radius, out,
                                                   masks, counts);
        scanemit_fill_tail<<<2048, 256, 0, stream>>>(masks, counts, out, row);
    } else {
        fill_kernel<<<2048, 256, 0, stream>>>(out, idx_count);
        int blocks = (m * 64 + 255) / 256;
        count_kernel<<<blocks, 256, 0, stream>>>(data, queries, radius, n, m, row);
        scan_kernel2<<<1, 1024, 0, stream>>>(row, row, m);
        emit_kernel<<<blocks, 256, 0, stream>>>(data, queries, radius, n, m, row, out);
    }
}